// Round 6
// baseline (128.189 us; speedup 1.0000x reference)
//
#include <hip/hip_runtime.h>
#include <hip/hip_bf16.h>

// MultiHeadAttention: S=2048, B=2, EMB=512, H=8, D=64 -> 16 (b,h) groups of
// [2048 x 64] attention + per-head 64x64 QKV proj + 512x512 output FC.
//
// R17: producer->consumer XCD co-location. R13-R16 showed flash invariant
// (~43-56 us) under occupancy x2, traffic /2, VALU /2, bank-conflicts /18:
// ~2900 stall cycles per wave-iter with nothing saturated. Remaining shared
// factor: proj scatters each group's Qf/Kf/Vf dirty lines across all 8
// non-coherent XCD L2s; flash re-pulls them cross-die every iteration.
// Fix (index swizzles only, bijective):
//  - proj: block bx%8==r writes groups g%8==r  -> writer XCD == flash
//    reader XCD (flash bi: g=bi&15, XCD bi%8=g%8).
//  - fc: M-block swizzle mb=4r+(j&3)+32(j>>2) -> fc reader XCD == flash
//    At-writer XCD.
//  - flash/fc inner loops byte-identical to R16.
//
// ws: [0)   Qf [g][qt 32][qs 2][s 4][lane 64][8] bf16 (Q pre-scaled 0.125*log2e)
//     [4M)  Kf [g][it 32][kh 2][s 4][lane 64][8] bf16
//     [8M)  Vf [g][it 32][kh 2][dc 2][s2 2][lane 64][8] bf16
//     [12M) At 32768x64 bf16
//     [16M) Wb 512x512 bf16
//     [16M+512K) KnSq[256] float

typedef __attribute__((ext_vector_type(8))) __bf16 bf16x8;
typedef __attribute__((ext_vector_type(4))) float f32x4;
typedef __attribute__((ext_vector_type(16))) float f32x16;
typedef __attribute__((ext_vector_type(4))) unsigned short u16x4;
typedef __attribute__((ext_vector_type(4))) unsigned int u32x4;
typedef __attribute__((ext_vector_type(2))) int i32x2;
typedef unsigned short u16;
typedef unsigned int u32;

static __device__ __forceinline__ u16 f2bf(float x) {
    u32 u = __float_as_uint(x);
    u += 0x7fff + ((u >> 16) & 1);   // RNE
    return (u16)(u >> 16);
}
static __device__ __forceinline__ float bf2f(u16 h) {
    return __uint_as_float(((u32)h) << 16);
}
// packed bf16x2 convert (prologue/epilogue use)
static __device__ __forceinline__ u32 pk2(float lo, float hi) {
    __hip_bfloat162 h2 = __float22bfloat162_rn(make_float2(lo, hi));
    u32 r; __builtin_memcpy(&r, &h2, 4); return r;
}
// single-instruction packed convert for the hot loop (guide T12 recipe)
static __device__ __forceinline__ u32 cvtpk(float lo, float hi) {
    u32 r;
    asm("v_cvt_pk_bf16_f32 %0, %1, %2" : "=v"(r) : "v"(lo), "v"(hi));
    return r;
}
// lane[i] <-> lane[i+32] half-exchange producing both fragment words
static __device__ __forceinline__ void halfswap(u32 &x, u32 &y) {
#if __has_builtin(__builtin_amdgcn_permlane32_swap)
    i32x2 r = __builtin_amdgcn_permlane32_swap((int)x, (int)y, false, false);
    x = (u32)r[0]; y = (u32)r[1];
#else
    int h = (threadIdx.x >> 5) & 1;
    u32 px = (u32)__shfl_xor((int)x, 32);
    u32 py = (u32)__shfl_xor((int)y, 32);
    u32 nx = h ? py : x;
    u32 ny = h ? y : px;
    x = nx; y = ny;
#endif
}
static __device__ __forceinline__ bf16x8 mk8(u32 w0, u32 w1, u32 w2, u32 w3) {
    u32x4 u = {w0, w1, w2, w3};
    bf16x8 r; __builtin_memcpy(&r, &u, 16); return r;
}

// ---------------------------------------------------------------------------
// Kernel 1: z=0/1/2 -> QKV projection (Y = X@W^T * scale) written in
// MFMA-fragment order; z=3 -> Wfc->bf16.  z=1 also writes KnSq per chunk.
// XCD swizzle: blocks with bx%8==r handle groups g%8==r, so the fragment
// lines stay dirty in the XCD L2 that flash will read them from.
// ---------------------------------------------------------------------------
__global__ __launch_bounds__(256) void proj_kernel(
    const float* __restrict__ q, const float* __restrict__ k, const float* __restrict__ v,
    const float* __restrict__ Wq, const float* __restrict__ Wk, const float* __restrict__ Wv,
    const float* __restrict__ Wfc,
    u16* __restrict__ Qf, u16* __restrict__ Kf, u16* __restrict__ Vf,
    u16* __restrict__ Wb, float* __restrict__ KnSq)
{
    const int mode = blockIdx.z;
    const int t = threadIdx.x;

    if (mode == 3) {
        int i = (blockIdx.x * 256 + t) * 4;
        float4 val = *(const float4*)(Wfc + i);
        uint2 b = { pk2(val.x, val.y), pk2(val.z, val.w) };
        *(uint2*)(Wb + i) = b;
        return;
    }

    const float* A = (mode == 0) ? q : (mode == 1) ? k : v;
    const float* W = (mode == 0) ? Wq : (mode == 1) ? Wk : Wv;
    const float osc = (mode == 0) ? 0.18033688011112042f : 1.0f; // 0.125*log2(e)

    __shared__ alignas(16) u16 Ash[128 * 88];   // input stage; reused as output stage
    __shared__ alignas(16) u16 Wsh[64 * 88];
    __shared__ float red[2];

    // XCD co-location swizzle (bijective on [0,256)):
    // r = bx%8 (XCD), j = bx/8; group g = r + 8*(j>>4), chunk t0c = j&15.
    const int bx = blockIdx.x;
    const int rX = bx & 7, jX = bx >> 3;
    const int m0 = ((rX + ((jX >> 4) << 3)) << 11) + ((jX & 15) << 7);

    const int w = t >> 6, l = t & 63;
    const int r16 = l & 15, q4 = l >> 4;

    {   // stage inputs (coalesced float4, pk-convert)
        const float4* A4 = (const float4*)(A + (size_t)m0 * 64);
        const int c4 = t & 15;
        #pragma unroll
        for (int i = 0; i < 8; ++i) {
            int row = (t >> 4) + i * 16;
            float4 val = A4[row * 16 + c4];
            uint2 bb = { pk2(val.x, val.y), pk2(val.z, val.w) };
            *(uint2*)(Ash + row * 88 + c4 * 4) = bb;
        }
        const float4* W4 = (const float4*)W;
        #pragma unroll
        for (int i = 0; i < 4; ++i) {
            int row = (t >> 4) + i * 16;
            float4 val = W4[row * 16 + c4];
            uint2 bb = { pk2(val.x, val.y), pk2(val.z, val.w) };
            *(uint2*)(Wsh + row * 88 + c4 * 4) = bb;
        }
    }
    __syncthreads();

    bf16x8 af[2][2], wf[4][2];
    #pragma unroll
    for (int mc = 0; mc < 2; ++mc)
        #pragma unroll
        for (int kk = 0; kk < 2; ++kk)
            af[mc][kk] = *(const bf16x8*)(Ash + (w * 32 + mc * 16 + r16) * 88 + kk * 32 + q4 * 8);
    #pragma unroll
    for (int nc = 0; nc < 4; ++nc)
        #pragma unroll
        for (int kk = 0; kk < 2; ++kk)
            wf[nc][kk] = *(const bf16x8*)(Wsh + (nc * 16 + r16) * 88 + kk * 32 + q4 * 8);

    f32x4 acc[2][4];
    const f32x4 zero = {0.f, 0.f, 0.f, 0.f};
    #pragma unroll
    for (int mc = 0; mc < 2; ++mc)
        #pragma unroll
        for (int nc = 0; nc < 4; ++nc) {
            acc[mc][nc] = __builtin_amdgcn_mfma_f32_16x16x32_bf16(af[mc][0], wf[nc][0], zero, 0, 0, 0);
            acc[mc][nc] = __builtin_amdgcn_mfma_f32_16x16x32_bf16(af[mc][1], wf[nc][1], acc[mc][nc], 0, 0, 0);
        }

    __syncthreads();   // done with input stage; reuse Ash

    const int g = m0 >> 11, t0 = (m0 & 2047) >> 6;   // group, first 64-tile

    // C/D layout: col(n) = lane&15, row(m) = quad*4 + reg
    if (mode < 2) {
        // store Y [128 rows][64] (scaled) into Ash with 72-stride
        #pragma unroll
        for (int mc = 0; mc < 2; ++mc)
            #pragma unroll
            for (int nc = 0; nc < 4; ++nc)
                #pragma unroll
                for (int r = 0; r < 4; ++r)
                    Ash[(w * 32 + mc * 16 + q4 * 4 + r) * 72 + nc * 16 + r16] = f2bf(acc[mc][nc][r] * osc);
        __syncthreads();
        // emit fragment order: [tile t0+tl][c2 (qs|kh)][s][lane][8]
        u16* Out = (mode == 0) ? Qf : Kf;
        #pragma unroll
        for (int i = 0; i < 4; ++i) {
            int idx = i * 256 + t;                 // [0,1024)
            int ll = idx & 63;
            int r = idx >> 6;                      // [0,16)
            int tl = r >> 3, c2 = (r >> 2) & 1, s = r & 3;
            int row = tl * 64 + c2 * 32 + (ll & 31);
            int col = s * 16 + (ll >> 5) * 8;
            u32x4 d = *(const u32x4*)(Ash + row * 72 + col);
            *(u32x4*)(Out + ((size_t)(((g * 32 + t0 + tl) * 2 + c2) * 4 + s) * 64 + ll) * 8) = d;
        }
        if (mode == 1) {   // per-chunk max ||K row||^2 via wave shfl reduce
            float ss = 0.f;
            if (t < 128) {
                #pragma unroll
                for (int c = 0; c < 8; ++c) {
                    u32x4 d = *(const u32x4*)(Ash + t * 72 + c * 8);
                    #pragma unroll
                    for (int j = 0; j < 4; ++j) {
                        float lo = bf2f((u16)(d[j] & 0xffff));
                        float hi = bf2f((u16)(d[j] >> 16));
                        ss += lo * lo + hi * hi;
                    }
                }
            }
            #pragma unroll
            for (int d = 1; d < 64; d <<= 1)
                ss = fmaxf(ss, __shfl_xor(ss, d));
            if (t < 128 && (t & 63) == 0) red[t >> 6] = ss;
            __syncthreads();
            // KnSq indexed by CHUNK position (g*16 + chunk), not blockIdx:
            // flash reads KnSq[g*16 + 0..15] as the 16 chunks of group g.
            if (t == 0) KnSq[g * 16 + ((m0 & 2047) >> 7)] = fmaxf(red[0], red[1]);
        }
    } else {
        // store V^T [64 d][128 keys] into Ash with 136-stride
        #pragma unroll
        for (int mc = 0; mc < 2; ++mc)
            #pragma unroll
            for (int nc = 0; nc < 4; ++nc)
                #pragma unroll
                for (int r = 0; r < 4; ++r)
                    Ash[(nc * 16 + r16) * 136 + w * 32 + mc * 16 + q4 * 4 + r] = f2bf(acc[mc][nc][r]);
        __syncthreads();
        // emit fragment order: [tile][kh][dc][s2][lane][8]
        #pragma unroll
        for (int i = 0; i < 4; ++i) {
            int idx = i * 256 + t;
            int ll = idx & 63;
            int r = idx >> 6;                       // [0,16)
            int tl = r >> 3, kh = (r >> 2) & 1, dc = (r >> 1) & 1, s2 = r & 1;
            int d = dc * 32 + (ll & 31);
            int keycol = tl * 64 + kh * 32 + s2 * 16 + (ll >> 5) * 8;
            u32x4 val = *(const u32x4*)(Ash + d * 136 + keycol);
            *(u32x4*)(Vf + ((size_t)((((g * 32 + t0 + tl) * 2 + kh) * 2 + dc) * 2 + s2) * 64 + ll) * 8) = val;
        }
    }
}

// ---------------------------------------------------------------------------
// Kernel 2: barrier-free flash on 32x32x16 MFMA, register Q-reuse, fully
// in-register softmax redistribution (no in-loop LDS).  [FROZEN = R15/R16]
// Block = 4 waves (key-quarters); each wave: 64 q (2 chains) x 512 keys,
// 16 iters. S^T C/D (q=lane&31, key=(r&3)+8(r>>2)+4h) -> PV B-frags via
// v_cvt_pk_bf16_f32 + permlane32_swap (2 swaps per 16-key frag).
// l-sum per lane over its 16 keys + one deferred shfl_xor(32).
// Epilogue: kq=1..3 dump partials (both qs) to LDS; kq==0 merges both.
// ---------------------------------------------------------------------------
__global__ __launch_bounds__(256) void flash_kernel(
    const u16* __restrict__ Qf, const u16* __restrict__ Kf,
    const u16* __restrict__ Vf, const float* __restrict__ KnSq,
    u16* __restrict__ Att)
{
    const int bi = blockIdx.x;
    const int g = bi & 15;        // XCD co-location (bi%8 == g%8 == proj writer XCD)
    const int qt = bi >> 4;       // 0..31
    const int t = threadIdx.x, w = t >> 6, l = t & 63;
    const int q5 = l & 31, h = l >> 5;
    const int kq = w;             // key quarter 0..3
    const int kh2 = kq & 1, th = kq >> 1;

    // epilogue-only LDS: Fsh 6 x [64][34] f32 [0,52224) ; Osh [64][72] u16 [52224,61440)
    __shared__ alignas(16) unsigned char smem[61440];

    // fragment bases (u16 units); per-iteration stride 4096 (= 2*4*512)
    const u16* qbase = Qf + ((size_t)((g * 32 + qt) * 2 * 4)) * 512 + l * 8;   // qs stride 2048
    const u16* kbase = Kf + ((size_t)(((g * 32 + th * 16) * 2 + kh2) * 4)) * 512 + l * 8;
    const u16* vbase = Vf + ((size_t)((((g * 32 + th * 16) * 2 + kh2) * 2) * 2)) * 512 + l * 8;

    bf16x8 qa[4], qc[4];
    #pragma unroll
    for (int s = 0; s < 4; ++s) {
        qa[s] = *(const bf16x8*)(qbase + s * 512);
        qc[s] = *(const bf16x8*)(qbase + 2048 + s * 512);
    }

    // fixed bound m[qs] = ||Qrow_scaled|| * max||K|| * margin (same across kq
    // waves for a given q-row -> partials over key quarters share the shift)
    float kss;
    {
        kss = KnSq[g * 16 + (l & 15)];
        kss = fmaxf(kss, __shfl_xor(kss, 1));
        kss = fmaxf(kss, __shfl_xor(kss, 2));
        kss = fmaxf(kss, __shfl_xor(kss, 4));
        kss = fmaxf(kss, __shfl_xor(kss, 8));
    }
    float m0v, m1v;
    {
        float ss0 = 0.f, ss1 = 0.f;
        #pragma unroll
        for (int s = 0; s < 4; ++s)
            #pragma unroll
            for (int j = 0; j < 8; ++j) {
                float x0 = (float)qa[s][j];
                float x1 = (float)qc[s][j];
                ss0 += x0 * x0;
                ss1 += x1 * x1;
            }
        ss0 += __shfl_xor(ss0, 32);
        ss1 += __shfl_xor(ss1, 32);
        m0v = sqrtf(ss0 * kss) * 1.0002f;
        m1v = sqrtf(ss1 * kss) * 1.0002f;
    }

    f32x16 mC0, mC1, o0a, o1a, o0b, o1b;
    #pragma unroll
    for (int r = 0; r < 16; ++r) {
        mC0[r] = -m0v; mC1[r] = -m1v;
        o0a[r] = 0.f; o1a[r] = 0.f; o0b[r] = 0.f; o1b[r] = 0.f;
    }
    float ls0 = 0.f, ls1 = 0.f;

    // prefetch tile 0
    bf16x8 ka[4], va[4], kan[4], van[4];
    #pragma unroll
    for (int s = 0; s < 4; ++s) ka[s] = *(const bf16x8*)(kbase + s * 512);
    #pragma unroll
    for (int j = 0; j < 4; ++j) va[j] = *(const bf16x8*)(vbase + j * 512);

    for (int it = 0; it < 16; ++it) {
        const size_t nx = (size_t)((it + 1) & 15) * 4096;
        #pragma unroll
        for (int s = 0; s < 4; ++s) kan[s] = *(const bf16x8*)(kbase + nx + s * 512);
        #pragma unroll
        for (int j = 0; j < 4; ++j) van[j] = *(const bf16x8*)(vbase + nx + j * 512);

        // ---- chain A: S^T = K.Q^T - m, exp2, in-register B-frag build ----
        f32x16 s0;
        s0 = __builtin_amdgcn_mfma_f32_32x32x16_bf16(ka[0], qa[0], mC0, 0, 0, 0);
        s0 = __builtin_amdgcn_mfma_f32_32x32x16_bf16(ka[1], qa[1], s0, 0, 0, 0);
        s0 = __builtin_amdgcn_mfma_f32_32x32x16_bf16(ka[2], qa[2], s0, 0, 0, 0);
        s0 = __builtin_amdgcn_mfma_f32_32x32x16_bf16(ka[3], qa[3], s0, 0, 0, 0);
        #pragma unroll
        for (int r = 0; r < 16; ++r) { s0[r] = exp2f(s0[r]); ls0 += s0[r]; }
        u32 a0 = cvtpk(s0[0],  s0[1]),  a1 = cvtpk(s0[2],  s0[3]);
        u32 b0 = cvtpk(s0[4],  s0[5]),  b1 = cvtpk(s0[6],  s0[7]);
        u32 c0 = cvtpk(s0[8],  s0[9]),  c1 = cvtpk(s0[10], s0[11]);
        u32 d0 = cvtpk(s0[12], s0[13]), d1 = cvtpk(s0[14], s0[15]);
        halfswap(a0, b0); halfswap(a1, b1);
        halfswap(c0, d0); halfswap(c1, d1);
        bf16x8 pa0 = mk8(a0, a1, b0, b1);   // keys h*8 + 0..7   (slot s2=0)
        bf16x8 pa1 = mk8(c0, c1, d0, d1);   // keys 16 + h*8 + 0..7 (slot s2=1)

        // ---- chain B ----
        f32x16 s1;
        s1 = __builtin_amdgcn_mfma_f32_32x32x16_bf16(ka[0], qc[0], mC1, 0, 0, 0);
        s1 = __builtin_amdgcn_mfma_f32_32x32x16_bf16(ka[1], qc[1], s1, 0, 0, 0);
        s1 = __builtin_amdgcn_mfma_f32_32x32x16_bf16(ka[2], qc[2], s1, 0, 0, 0);
        s1 = __builtin_amdgcn_mfma_f32_32x32x16_bf16(ka[3], qc[3], s1, 0, 0, 0);
        #pragma unroll
        for (int r = 0; r < 16; ++r) { s1[r] = exp2f(s1[r]); ls1 += s1[r]; }
        u32 e0 = cvtpk(s1[0],  s1[1]),  e1 = cvtpk(s1[2],  s1[3]);
        u32 f0 = cvtpk(s1[4],  s1[5]),  f1 = cvtpk(s1[6],  s1[7]);
        u32 g0 = cvtpk(s1[8],  s1[9]),  g1 = cvtpk(s1[10], s1[11]);
        u32 h0 = cvtpk(s1[12], s1[13]), h1 = cvtpk(s1[14], s1[15]);
        halfswap(e0, f0); halfswap(e1, f1);
        halfswap(g0, h0); halfswap(g1, h1);
        bf16x8 pb0 = mk8(e0, e1, f0, f1);
        bf16x8 pb1 = mk8(g0, g1, h0, h1);

        // ---- PV: two independent chains share va[] ----
        o0a = __builtin_amdgcn_mfma_f32_32x32x16_bf16(va[0], pa0, o0a, 0, 0, 0);
        o0b = __builtin_amdgcn_mfma_f32_32x32x16_bf16(va[0], pb0, o0b, 0, 0, 0);
        o0a = __builtin_amdgcn_mfma_f32_32x32x16_bf16(va[1], pa1, o0a, 0, 0, 0);
        o0b = __builtin_amdgcn_mfma_f32_32x32x16_bf16(va[1], pb1, o0b, 0, 0, 0);
        o1a = __builtin_amdgcn_mfma_f32_32x32x16_bf16(va[2], pa0, o1a, 0, 0, 0);
        o1b = __builtin_amdgcn_mfma_f32_32x32x16_bf16(va[2], pb0, o1b, 0, 0, 0);
        o1a = __builtin_amdgcn_mfma_f32_32x32x16_bf16(va[3], pa1, o1a, 0, 0, 0);
        o1b = __builtin_amdgcn_mfma_f32_32x32x16_bf16(va[3], pb1, o1b, 0, 0, 0);

        #pragma unroll
        for (int s2 = 0; s2 < 4; ++s2) { ka[s2] = kan[s2]; va[s2] = van[s2]; }
    }

    // ---- epilogue: merge 4 key-quarters (both qs), normalize, store ----
    float psq0 = ls0 + __shfl_xor(ls0, 32);     // l[q5] for qs=0, all lanes
    float psq1 = ls1 + __shfl_xor(ls1, 32);     // l[q5] for qs=1

    float* const Fsh = (float*)smem;            // 6 bufs x [64 lanes][34]
    u16*  const Osh = (u16*)(smem + 52224);     // [64 q][72]

    __syncthreads();
    if (kq != 0) {
        float* f0p = Fsh + (0 * 3 + (kq - 1)) * (64 * 34) + l * 34;
        float* f1p = Fsh + (1 * 3 + (kq - 1)) * (64 * 34) + l * 34;
        #pragma unroll
        for (int r = 0; r < 16; ++r) {
            f0p[r] = o0a[r]; f0p[16 + r] = o1a[r];
            f1p[r] = o0b[r]; f1p[16 + r] = o1b[r];
        }
        f0p[32] = psq0;
        f1p[32] = psq1;
    }
    __syncthreads();
    if (kq == 0) {
        // qs = 0
        {
            float ltot = psq0;
            #pragma unroll
            for (int b = 0; b < 3; ++b) {
                const float* fp = Fsh + (0 * 3 + b) * (64 * 34) + l * 34;
                ltot += fp[32];
                #pragma unroll
                for (int r = 0; r < 16; ++r) { o0a[r] += fp[r]; o1a[r] += fp[16 + r]; }
            }
            float inv = 1.0f / ltot;
            #pragma unroll
            for (int u = 0; u < 4; ++u) {
                uint2 w0 = { pk2(o0a[4*u+0] * inv, o0a[4*u+1] * inv),
                             pk2(o0a[4*u+2] * inv, o0a[4*u+3] * inv) };
                *(uint2*)(Osh + q5 * 72 + 8 * u + 4 * h) = w0;
                uint2 w1 = { pk2(o1a[4*u+0] * inv, o1a[4*u+1] * inv),
                             pk2(o1a[4*u+2] * inv, o1a[4*u+3] * inv) };
                *(uint2*)(Osh + q5 * 72 + 32 + 8 * u + 4 * h) = w1;
            }
        }
        // qs = 1
        {
            float ltot = psq1;
            #pragma unroll
            for (int b = 0; b < 3; ++b) {
                const float* fp = Fsh + (1 * 3 + b) * (64 * 34) + l * 34;
                ltot += fp[32];
                #pragma unroll
                for (int r = 0; r < 16; ++r) { o0b[r] += fp[r]; o1b[r] += fp[16 + r]; }
            }
            float inv = 1.0f / ltot;
            const int qloc = 32 + q5;
            #pragma unroll
            for (int u = 0; u < 4; ++u) {
                uint2 w0 = { pk2(o0b[4*u+0] * inv, o0b[4*u+1] * inv),
                             pk2(o0b[4*u+2] * inv, o0b[4*u+3] * inv) };
                *(uint2*)(Osh + qloc * 72 + 8 * u + 4 * h) = w0;
                uint2 w1 = { pk2(o1b[4*u+0] * inv, o1b[4*u+1] * inv),
                             pk2(o1b[4*u+2] * inv, o1b[4*u+3] * inv) };
                *(uint2*)(Osh + qloc * 72 + 32 + 8 * u + 4 * h) = w1;
            }
        }
    }
    __syncthreads();
    {   // coalesced copy Osh -> Att (256 threads, two b128 each)
        int row = t >> 2, cb = (t & 3) * 16;
        u16* dst = Att + ((size_t)(g * 2048 + qt * 64 + row)) * 64 + cb;
        *(u32x4*)(dst)     = *(const u32x4*)(Osh + row * 72 + cb);
        *(u32x4*)(dst + 8) = *(const u32x4*)(Osh + row * 72 + cb + 8);
    }
}

// ---------------------------------------------------------------------------
// Kernel 3: out = Att @ Wb^T + bfc (Wb bf16).  BK=128 double-buffer:
// LDS [2 buf][2 sub][64][64] u16 (64 KB), 4 K-iters, one barrier each.
// M-block XCD swizzle: fc block at XCD bx%8 reads At rows whose flash
// writer was on the same XCD (At group of row-block mb = mb/4; writer
// XCD (mb/4)%8; mb = 4r + (j&3) + 32*(j>>2) is bijective on [0,64)).
// BM=64, BN=64; grid (64,8).
// ---------------------------------------------------------------------------
__global__ __launch_bounds__(256) void fc_kernel(
    const u16* __restrict__ Att, const u16* __restrict__ Wb,
    const float* __restrict__ bfc, float* __restrict__ out)
{
    __shared__ alignas(16) u16 Ash[2][2][64 * 64];
    __shared__ alignas(16) u16 Wsh[2][2][64 * 64];

    const int t = threadIdx.x, w = t >> 6, l = t & 63;
    const int r16 = l & 15, q4 = l >> 4;
    const int r7 = r16 & 7;

    const int bxl = blockIdx.x;
    const int rX = bxl & 7, jX = bxl >> 3;
    const int mb = rX * 4 + (jX & 3) + ((jX >> 2) << 5);
    const int m0 = mb * 64, n0 = blockIdx.y * 64;

    const int rr = t >> 3, ck = t & 7;
    const int sw0 = (ck ^ (rr & 7)) * 8;
    const int fr0 = (q4 ^ r7) * 8;
    const int fr1 = ((q4 + 4) ^ r7) * 8;

    {   // stage chunk 0 (k 0..127) into buf 0
        #pragma unroll
        for (int hh = 0; hh < 2; ++hh)
            #pragma unroll
            for (int s = 0; s < 2; ++s) {
                int row = hh * 32 + rr;
                int kof = s * 64 + ck * 8;
                *(u32x4*)(&Ash[0][s][row * 64 + sw0]) = *(const u32x4*)(Att + (size_t)(m0 + row) * 512 + kof);
                *(u32x4*)(&Wsh[0][s][row * 64 + sw0]) = *(const u32x4*)(Wb + (size_t)(n0 + row) * 512 + kof);
            }
    }
    __syncthreads();

    f32x4 acc[4];
    const f32x4 zero = {0.f, 0.f, 0.f, 0.f};
    #pragma unroll
    for (int nc = 0; nc < 4; ++nc) acc[nc] = zero;

    for (int c = 0; c < 4; ++c) {
        const int cur = c & 1;
        const bool hasn = (c < 3);

        u32x4 an[4], wn[4];
        if (hasn) {
            #pragma unroll
            for (int hh = 0; hh < 2; ++hh)
                #pragma unroll
                for (int s = 0; s < 2; ++s) {
                    int row = hh * 32 + rr;
                    int kof = (c + 1) * 128 + s * 64 + ck * 8;
                    an[hh * 2 + s] = *(const u32x4*)(Att + (size_t)(m0 + row) * 512 + kof);
                    wn[hh * 2 + s] = *(const u32x4*)(Wb + (size_t)(n0 + row) * 512 + kof);
                }
        }

        #pragma unroll
        for (int s = 0; s < 2; ++s) {
            bf16x8 af0 = *(const bf16x8*)(&Ash[cur][s][(w * 16 + r16) * 64 + fr0]);
            bf16x8 af1 = *(const bf16x8*)(&Ash[cur][s][(w * 16 + r16) * 64 + fr1]);
            #pragma unroll
            for (int nc = 0; nc < 4; ++nc) {
                bf16x8 wf0 = *(const bf16x8*)(&Wsh[cur][s][(nc * 16 + r16) * 64 + fr0]);
                bf16x8 wf1 = *(const bf16x8*)(&Wsh[cur][s][(nc * 16 + r16) * 64 + fr1]);
                acc[nc] = __builtin_amdgcn_mfma_f32_16x16x32_bf16(af0, wf0, acc[nc], 0, 0, 0);
                acc[nc] = __builtin_amdgcn_mfma_f32_16x16x32_bf16(af1, wf1, acc[nc], 0, 0, 0);
            }
        }

        if (hasn) {
            const int nxt = cur ^ 1;
            #pragma unroll
            for (int hh = 0; hh < 2; ++hh)
                #pragma unroll
                for (int s = 0; s < 2; ++s) {
                    int row = hh * 32 + rr;
                    *(u32x4*)(&Ash[nxt][s][row * 64 + sw0]) = an[hh * 2 + s];
                    *(u32x4*)(&Wsh[nxt][s][row * 64 + sw0]) = wn[hh * 2 + s];
                }
        }
        __syncthreads();
    }

    #pragma unroll
    for (int nc = 0; nc < 4; ++nc) {
        float bb = bfc[n0 + nc * 16 + r16];
        #pragma unroll
        for (int r = 0; r < 4; ++r) {
            int row = m0 + w * 16 + q4 * 4 + r;
            out[(size_t)row * 512 + n0 + nc * 16 + r16] = acc[nc][r] + bb;
        }
    }
}

extern "C" void kernel_launch(void* const* d_in, const int* in_sizes, int n_in,
                              void* d_out, int out_size, void* d_ws, size_t ws_size,
                              hipStream_t stream) {
    (void)in_sizes; (void)n_in; (void)out_size; (void)ws_size;
    const float* q   = (const float*)d_in[0];
    const float* k   = (const float*)d_in[1];
    const float* v   = (const float*)d_in[2];
    const float* Wq  = (const float*)d_in[3];
    const float* Wk  = (const float*)d_in[4];
    const float* Wv  = (const float*)d_in[5];
    const float* Wfc = (const float*)d_in[6];
    const float* bfc = (const float*)d_in[7];
    float* out = (float*)d_out;

    u16* Qf = (u16*)d_ws;
    u16* Kf = Qf + 2097152;
    u16* Vf = Kf + 2097152;
    u16* At = Vf + 2097152;
    u16* Wb = At + 2097152;
    float* KnSq = (float*)((char*)d_ws + 17301504);

    proj_kernel<<<dim3(256, 1, 4), 256, 0, stream>>>(q, k, v, Wq, Wk, Wv, Wfc,
                                                     Qf, Kf, Vf, Wb, KnSq);
    flash_kernel<<<dim3(512), 256, 0, stream>>>(Qf, Kf, Vf, KnSq, At);
    fc_kernel<<<dim3(64, 8), 256, 0, stream>>>(At, Wb, bfc, out);
}

// Round 7
// 118.625 us; speedup vs baseline: 1.0806x; 1.0806x over previous
//
#include <hip/hip_runtime.h>
#include <hip/hip_bf16.h>

// MultiHeadAttention: S=2048, B=2, EMB=512, H=8, D=64 -> 16 (b,h) groups of
// [2048 x 64] attention + per-head 64x64 QKV proj + 512x512 output FC.
//
// R18: flash occupancy retry on the R15 (in-register-softmax) structure.
// Cross-round fit: total = ~86us harness fills + flash; flash stuck ~41us
// vs ~13us work floor, latency-bound at 2 waves/SIMD (R13's occupancy null
// was on the old VALU-bound structure; doesn't transfer). Now: 512 blocks
// x 8 waves (qs-half x key-quarter, SINGLE chain/wave), no cross-iter
// register prefetch (TLP hides L2 latency; kills the kan->ka mov spam),
// __launch_bounds__(512,4) -> <=128 VGPR, 4 waves/SIMD, 2 blocks/CU.
// Softmax fully in-register (cvt_pk + permlane32_swap, R15-verified);
// epilogue = R13-verified 6-buf merge. proj/fc = R16 verbatim.
//
// ws: [0)   Qf [g][qt 32][qs 2][s 4][lane 64][8] bf16 (Q pre-scaled 0.125*log2e)
//     [4M)  Kf [g][it 32][kh 2][s 4][lane 64][8] bf16
//     [8M)  Vf [g][it 32][kh 2][dc 2][s2 2][lane 64][8] bf16
//     [12M) At 32768x64 bf16
//     [16M) Wb 512x512 bf16
//     [16M+512K) KnSq[256] float

typedef __attribute__((ext_vector_type(8))) __bf16 bf16x8;
typedef __attribute__((ext_vector_type(4))) float f32x4;
typedef __attribute__((ext_vector_type(16))) float f32x16;
typedef __attribute__((ext_vector_type(4))) unsigned short u16x4;
typedef __attribute__((ext_vector_type(4))) unsigned int u32x4;
typedef __attribute__((ext_vector_type(2))) int i32x2;
typedef unsigned short u16;
typedef unsigned int u32;

static __device__ __forceinline__ u16 f2bf(float x) {
    u32 u = __float_as_uint(x);
    u += 0x7fff + ((u >> 16) & 1);   // RNE
    return (u16)(u >> 16);
}
static __device__ __forceinline__ float bf2f(u16 h) {
    return __uint_as_float(((u32)h) << 16);
}
// packed bf16x2 convert (prologue/epilogue use)
static __device__ __forceinline__ u32 pk2(float lo, float hi) {
    __hip_bfloat162 h2 = __float22bfloat162_rn(make_float2(lo, hi));
    u32 r; __builtin_memcpy(&r, &h2, 4); return r;
}
// single-instruction packed convert for the hot loop (guide T12 recipe)
static __device__ __forceinline__ u32 cvtpk(float lo, float hi) {
    u32 r;
    asm("v_cvt_pk_bf16_f32 %0, %1, %2" : "=v"(r) : "v"(lo), "v"(hi));
    return r;
}
// lane[i] <-> lane[i+32] half-exchange producing both fragment words
static __device__ __forceinline__ void halfswap(u32 &x, u32 &y) {
#if __has_builtin(__builtin_amdgcn_permlane32_swap)
    i32x2 r = __builtin_amdgcn_permlane32_swap((int)x, (int)y, false, false);
    x = (u32)r[0]; y = (u32)r[1];
#else
    int h = (threadIdx.x >> 5) & 1;
    u32 px = (u32)__shfl_xor((int)x, 32);
    u32 py = (u32)__shfl_xor((int)y, 32);
    u32 nx = h ? py : x;
    u32 ny = h ? y : px;
    x = nx; y = ny;
#endif
}
static __device__ __forceinline__ bf16x8 mk8(u32 w0, u32 w1, u32 w2, u32 w3) {
    u32x4 u = {w0, w1, w2, w3};
    bf16x8 r; __builtin_memcpy(&r, &u, 16); return r;
}

// ---------------------------------------------------------------------------
// Kernel 1: z=0/1/2 -> QKV projection (Y = X@W^T * scale) written in
// MFMA-fragment order; z=3 -> Wfc->bf16.  z=1 also writes KnSq[bx].
// ---------------------------------------------------------------------------
__global__ __launch_bounds__(256) void proj_kernel(
    const float* __restrict__ q, const float* __restrict__ k, const float* __restrict__ v,
    const float* __restrict__ Wq, const float* __restrict__ Wk, const float* __restrict__ Wv,
    const float* __restrict__ Wfc,
    u16* __restrict__ Qf, u16* __restrict__ Kf, u16* __restrict__ Vf,
    u16* __restrict__ Wb, float* __restrict__ KnSq)
{
    const int mode = blockIdx.z;
    const int t = threadIdx.x;

    if (mode == 3) {
        int i = (blockIdx.x * 256 + t) * 4;
        float4 val = *(const float4*)(Wfc + i);
        uint2 b = { pk2(val.x, val.y), pk2(val.z, val.w) };
        *(uint2*)(Wb + i) = b;
        return;
    }

    const float* A = (mode == 0) ? q : (mode == 1) ? k : v;
    const float* W = (mode == 0) ? Wq : (mode == 1) ? Wk : Wv;
    const float osc = (mode == 0) ? 0.18033688011112042f : 1.0f; // 0.125*log2(e)

    __shared__ alignas(16) u16 Ash[128 * 88];   // input stage; reused as output stage
    __shared__ alignas(16) u16 Wsh[64 * 88];
    __shared__ float red[2];

    const int m0 = blockIdx.x * 128;
    const int w = t >> 6, l = t & 63;
    const int r16 = l & 15, q4 = l >> 4;

    {   // stage inputs (coalesced float4, pk-convert)
        const float4* A4 = (const float4*)(A + (size_t)m0 * 64);
        const int c4 = t & 15;
        #pragma unroll
        for (int i = 0; i < 8; ++i) {
            int row = (t >> 4) + i * 16;
            float4 val = A4[row * 16 + c4];
            uint2 bb = { pk2(val.x, val.y), pk2(val.z, val.w) };
            *(uint2*)(Ash + row * 88 + c4 * 4) = bb;
        }
        const float4* W4 = (const float4*)W;
        #pragma unroll
        for (int i = 0; i < 4; ++i) {
            int row = (t >> 4) + i * 16;
            float4 val = W4[row * 16 + c4];
            uint2 bb = { pk2(val.x, val.y), pk2(val.z, val.w) };
            *(uint2*)(Wsh + row * 88 + c4 * 4) = bb;
        }
    }
    __syncthreads();

    bf16x8 af[2][2], wf[4][2];
    #pragma unroll
    for (int mc = 0; mc < 2; ++mc)
        #pragma unroll
        for (int kk = 0; kk < 2; ++kk)
            af[mc][kk] = *(const bf16x8*)(Ash + (w * 32 + mc * 16 + r16) * 88 + kk * 32 + q4 * 8);
    #pragma unroll
    for (int nc = 0; nc < 4; ++nc)
        #pragma unroll
        for (int kk = 0; kk < 2; ++kk)
            wf[nc][kk] = *(const bf16x8*)(Wsh + (nc * 16 + r16) * 88 + kk * 32 + q4 * 8);

    f32x4 acc[2][4];
    const f32x4 zero = {0.f, 0.f, 0.f, 0.f};
    #pragma unroll
    for (int mc = 0; mc < 2; ++mc)
        #pragma unroll
        for (int nc = 0; nc < 4; ++nc) {
            acc[mc][nc] = __builtin_amdgcn_mfma_f32_16x16x32_bf16(af[mc][0], wf[nc][0], zero, 0, 0, 0);
            acc[mc][nc] = __builtin_amdgcn_mfma_f32_16x16x32_bf16(af[mc][1], wf[nc][1], acc[mc][nc], 0, 0, 0);
        }

    __syncthreads();   // done with input stage; reuse Ash

    const int g = m0 >> 11, t0 = (m0 & 2047) >> 6;   // group, first 64-tile

    // C/D layout: col(n) = lane&15, row(m) = quad*4 + reg
    if (mode < 2) {
        // store Y [128 rows][64] (scaled) into Ash with 72-stride
        #pragma unroll
        for (int mc = 0; mc < 2; ++mc)
            #pragma unroll
            for (int nc = 0; nc < 4; ++nc)
                #pragma unroll
                for (int r = 0; r < 4; ++r)
                    Ash[(w * 32 + mc * 16 + q4 * 4 + r) * 72 + nc * 16 + r16] = f2bf(acc[mc][nc][r] * osc);
        __syncthreads();
        // emit fragment order: [tile t0+tl][c2 (qs|kh)][s][lane][8]
        u16* Out = (mode == 0) ? Qf : Kf;
        #pragma unroll
        for (int i = 0; i < 4; ++i) {
            int idx = i * 256 + t;                 // [0,1024)
            int ll = idx & 63;
            int r = idx >> 6;                      // [0,16)
            int tl = r >> 3, c2 = (r >> 2) & 1, s = r & 3;
            int row = tl * 64 + c2 * 32 + (ll & 31);
            int col = s * 16 + (ll >> 5) * 8;
            u32x4 d = *(const u32x4*)(Ash + row * 72 + col);
            *(u32x4*)(Out + ((size_t)(((g * 32 + t0 + tl) * 2 + c2) * 4 + s) * 64 + ll) * 8) = d;
        }
        if (mode == 1) {   // per-block max ||K row||^2 via wave shfl reduce
            float ss = 0.f;
            if (t < 128) {
                #pragma unroll
                for (int c = 0; c < 8; ++c) {
                    u32x4 d = *(const u32x4*)(Ash + t * 72 + c * 8);
                    #pragma unroll
                    for (int j = 0; j < 4; ++j) {
                        float lo = bf2f((u16)(d[j] & 0xffff));
                        float hi = bf2f((u16)(d[j] >> 16));
                        ss += lo * lo + hi * hi;
                    }
                }
            }
            #pragma unroll
            for (int d = 1; d < 64; d <<= 1)
                ss = fmaxf(ss, __shfl_xor(ss, d));
            if (t < 128 && (t & 63) == 0) red[t >> 6] = ss;
            __syncthreads();
            if (t == 0) KnSq[blockIdx.x] = fmaxf(red[0], red[1]);
        }
    } else {
        // store V^T [64 d][128 keys] into Ash with 136-stride
        #pragma unroll
        for (int mc = 0; mc < 2; ++mc)
            #pragma unroll
            for (int nc = 0; nc < 4; ++nc)
                #pragma unroll
                for (int r = 0; r < 4; ++r)
                    Ash[(nc * 16 + r16) * 136 + w * 32 + mc * 16 + q4 * 4 + r] = f2bf(acc[mc][nc][r]);
        __syncthreads();
        // emit fragment order: [tile][kh][dc][s2][lane][8]
        #pragma unroll
        for (int i = 0; i < 4; ++i) {
            int idx = i * 256 + t;
            int ll = idx & 63;
            int r = idx >> 6;                       // [0,16)
            int tl = r >> 3, kh = (r >> 2) & 1, dc = (r >> 1) & 1, s2 = r & 1;
            int d = dc * 32 + (ll & 31);
            int keycol = tl * 64 + kh * 32 + s2 * 16 + (ll >> 5) * 8;
            u32x4 val = *(const u32x4*)(Ash + d * 136 + keycol);
            *(u32x4*)(Vf + ((size_t)((((g * 32 + t0 + tl) * 2 + kh) * 2 + dc) * 2 + s2) * 64 + ll) * 8) = val;
        }
    }
}

// ---------------------------------------------------------------------------
// Kernel 2: barrier-free flash, 8 waves/block (qs-half x key-quarter),
// single QK/PV chain per wave, fully in-register softmax, no cross-iter
// register prefetch (TLP at 4 waves/SIMD hides L2 latency).
// Each wave: 32 q rows x 512 keys, 16 iters of one 32-key tile.
// S^T C/D (q=lane&31, key=(r&3)+8(r>>2)+4h) -> PV B-frags via
// v_cvt_pk_bf16_f32 + permlane32_swap; l-sum per lane + shfl_xor(32).
// Epilogue (R13-verified): kq=1..3 dump partials to LDS; kq==0 merges.
// ---------------------------------------------------------------------------
__global__ __launch_bounds__(512, 4) void flash_kernel(
    const u16* __restrict__ Qf, const u16* __restrict__ Kf,
    const u16* __restrict__ Vf, const float* __restrict__ KnSq,
    u16* __restrict__ Att)
{
    const int bi = blockIdx.x;
    const int g = bi & 15;        // XCD co-location (bi%8 == g%8)
    const int qt = bi >> 4;       // 0..31
    const int t = threadIdx.x, w = t >> 6, l = t & 63;
    const int q5 = l & 31, h = l >> 5;
    const int qs = w >> 2;        // q 32-row half
    const int kq = w & 3;         // key quarter
    const int kh2 = kq & 1, th = kq >> 1;

    // epilogue-only LDS: Fsh 6 x [64][34] f32 [0,52224) ; Osh [64][72] u16 [52224,61440)
    __shared__ alignas(16) unsigned char smem[61440];

    // fragment bases (u16 units); per-iteration stride 4096 (= 2*4*512)
    const u16* qbase = Qf + ((size_t)(((g * 32 + qt) * 2 + qs) * 4)) * 512 + l * 8;
    const u16* kbase = Kf + ((size_t)(((g * 32 + th * 16) * 2 + kh2) * 4)) * 512 + l * 8;
    const u16* vbase = Vf + ((size_t)((((g * 32 + th * 16) * 2 + kh2) * 2) * 2)) * 512 + l * 8;

    bf16x8 qb[4];
    #pragma unroll
    for (int s = 0; s < 4; ++s) qb[s] = *(const bf16x8*)(qbase + s * 512);

    // fixed bound m = ||Qrow_scaled|| * max||K|| * margin (same across kq
    // waves for a given q-row -> partials over key quarters share the shift)
    float m;
    {
        float kss = KnSq[g * 16 + (l & 15)];
        kss = fmaxf(kss, __shfl_xor(kss, 1));
        kss = fmaxf(kss, __shfl_xor(kss, 2));
        kss = fmaxf(kss, __shfl_xor(kss, 4));
        kss = fmaxf(kss, __shfl_xor(kss, 8));
        float ss = 0.f;
        #pragma unroll
        for (int s = 0; s < 4; ++s)
            #pragma unroll
            for (int j = 0; j < 8; ++j) {
                float x = (float)qb[s][j];
                ss += x * x;
            }
        ss += __shfl_xor(ss, 32);
        m = sqrtf(ss * kss) * 1.0002f;
    }

    f32x16 mC, o0, o1;
    #pragma unroll
    for (int r = 0; r < 16; ++r) { mC[r] = -m; o0[r] = 0.f; o1[r] = 0.f; }
    float ls = 0.f;

    for (int it = 0; it < 16; ++it) {
        const size_t ofs = (size_t)it * 4096;
        bf16x8 ka0 = *(const bf16x8*)(kbase + ofs);
        bf16x8 ka1 = *(const bf16x8*)(kbase + ofs + 512);
        bf16x8 ka2 = *(const bf16x8*)(kbase + ofs + 1024);
        bf16x8 ka3 = *(const bf16x8*)(kbase + ofs + 1536);
        bf16x8 va0 = *(const bf16x8*)(vbase + ofs);
        bf16x8 va1 = *(const bf16x8*)(vbase + ofs + 512);
        bf16x8 va2 = *(const bf16x8*)(vbase + ofs + 1024);
        bf16x8 va3 = *(const bf16x8*)(vbase + ofs + 1536);

        // S^T = K.Q^T - m  (C operand = -m)
        f32x16 s;
        s = __builtin_amdgcn_mfma_f32_32x32x16_bf16(ka0, qb[0], mC, 0, 0, 0);
        s = __builtin_amdgcn_mfma_f32_32x32x16_bf16(ka1, qb[1], s, 0, 0, 0);
        s = __builtin_amdgcn_mfma_f32_32x32x16_bf16(ka2, qb[2], s, 0, 0, 0);
        s = __builtin_amdgcn_mfma_f32_32x32x16_bf16(ka3, qb[3], s, 0, 0, 0);

        // p = exp2(s) (already shifted); lane l-partial over its 16 keys
        #pragma unroll
        for (int r = 0; r < 16; ++r) { s[r] = exp2f(s[r]); ls += s[r]; }

        // in-register P -> B-frag build (cvt_pk + permlane32_swap)
        u32 a0 = cvtpk(s[0],  s[1]),  a1 = cvtpk(s[2],  s[3]);
        u32 b0 = cvtpk(s[4],  s[5]),  b1 = cvtpk(s[6],  s[7]);
        u32 c0 = cvtpk(s[8],  s[9]),  c1 = cvtpk(s[10], s[11]);
        u32 d0 = cvtpk(s[12], s[13]), d1 = cvtpk(s[14], s[15]);
        halfswap(a0, b0); halfswap(a1, b1);
        halfswap(c0, d0); halfswap(c1, d1);
        bf16x8 pa0 = mk8(a0, a1, b0, b1);   // keys h*8 + 0..7   (slot s2=0)
        bf16x8 pa1 = mk8(c0, c1, d0, d1);   // keys 16 + h*8 + 0..7 (slot s2=1)

        // PV
        o0 = __builtin_amdgcn_mfma_f32_32x32x16_bf16(va0, pa0, o0, 0, 0, 0);
        o0 = __builtin_amdgcn_mfma_f32_32x32x16_bf16(va1, pa1, o0, 0, 0, 0);
        o1 = __builtin_amdgcn_mfma_f32_32x32x16_bf16(va2, pa0, o1, 0, 0, 0);
        o1 = __builtin_amdgcn_mfma_f32_32x32x16_bf16(va3, pa1, o1, 0, 0, 0);
    }

    // ---- epilogue: merge 4 key-quarters per qs, normalize, store ----
    float psq = ls + __shfl_xor(ls, 32);        // l[q5], all lanes

    float* const Fsh = (float*)smem;            // 6 bufs x [64 lanes][34]
    u16*  const Osh = (u16*)(smem + 52224);     // [64 q][72]

    __syncthreads();
    if (kq != 0) {
        float* fp = Fsh + ((qs * 3) + (kq - 1)) * (64 * 34) + l * 34;
        #pragma unroll
        for (int r = 0; r < 16; ++r) { fp[r] = o0[r]; fp[16 + r] = o1[r]; }
        fp[32] = psq;
    }
    __syncthreads();
    if (kq == 0) {
        float ltot = psq;
        #pragma unroll
        for (int b = 0; b < 3; ++b) {
            const float* fp = Fsh + (qs * 3 + b) * (64 * 34) + l * 34;
            ltot += fp[32];
            #pragma unroll
            for (int r = 0; r < 16; ++r) { o0[r] += fp[r]; o1[r] += fp[16 + r]; }
        }
        float inv = 1.0f / ltot;
        const int qloc = qs * 32 + q5;
        #pragma unroll
        for (int u = 0; u < 4; ++u) {
            uint2 w0 = { pk2(o0[4*u+0] * inv, o0[4*u+1] * inv),
                         pk2(o0[4*u+2] * inv, o0[4*u+3] * inv) };
            *(uint2*)(Osh + qloc * 72 + 8 * u + 4 * h) = w0;
            uint2 w1 = { pk2(o1[4*u+0] * inv, o1[4*u+1] * inv),
                         pk2(o1[4*u+2] * inv, o1[4*u+3] * inv) };
            *(uint2*)(Osh + qloc * 72 + 32 + 8 * u + 4 * h) = w1;
        }
    }
    __syncthreads();
    {   // coalesced copy Osh -> Att (512 threads, one b128 each)
        int row = t >> 3, cb = (t & 7) * 8;
        u16* dst = Att + ((size_t)(g * 2048 + qt * 64 + row)) * 64 + cb;
        *(u32x4*)(dst) = *(const u32x4*)(Osh + row * 72 + cb);
    }
}

// ---------------------------------------------------------------------------
// Kernel 3: out = Att @ Wb^T + bfc (Wb bf16).  BK=128 double-buffer:
// LDS [2 buf][2 sub][64][64] u16 (64 KB), 4 K-iters, one barrier each,
// 16 MFMAs per barrier, prefetch issued before the MFMA cluster.
// BM=64, BN=64; grid (64,8).
// ---------------------------------------------------------------------------
__global__ __launch_bounds__(256) void fc_kernel(
    const u16* __restrict__ Att, const u16* __restrict__ Wb,
    const float* __restrict__ bfc, float* __restrict__ out)
{
    __shared__ alignas(16) u16 Ash[2][2][64 * 64];
    __shared__ alignas(16) u16 Wsh[2][2][64 * 64];

    const int t = threadIdx.x, w = t >> 6, l = t & 63;
    const int r16 = l & 15, q4 = l >> 4;
    const int r7 = r16 & 7;
    const int m0 = blockIdx.x * 64, n0 = blockIdx.y * 64;

    const int rr = t >> 3, ck = t & 7;
    const int sw0 = (ck ^ (rr & 7)) * 8;
    const int fr0 = (q4 ^ r7) * 8;
    const int fr1 = ((q4 + 4) ^ r7) * 8;

    {   // stage chunk 0 (k 0..127) into buf 0
        #pragma unroll
        for (int hh = 0; hh < 2; ++hh)
            #pragma unroll
            for (int s = 0; s < 2; ++s) {
                int row = hh * 32 + rr;
                int kof = s * 64 + ck * 8;
                *(u32x4*)(&Ash[0][s][row * 64 + sw0]) = *(const u32x4*)(Att + (size_t)(m0 + row) * 512 + kof);
                *(u32x4*)(&Wsh[0][s][row * 64 + sw0]) = *(const u32x4*)(Wb + (size_t)(n0 + row) * 512 + kof);
            }
    }
    __syncthreads();

    f32x4 acc[4];
    const f32x4 zero = {0.f, 0.f, 0.f, 0.f};
    #pragma unroll
    for (int nc = 0; nc < 4; ++nc) acc[nc] = zero;

    for (int c = 0; c < 4; ++c) {
        const int cur = c & 1;
        const bool hasn = (c < 3);

        u32x4 an[4], wn[4];
        if (hasn) {
            #pragma unroll
            for (int hh = 0; hh < 2; ++hh)
                #pragma unroll
                for (int s = 0; s < 2; ++s) {
                    int row = hh * 32 + rr;
                    int kof = (c + 1) * 128 + s * 64 + ck * 8;
                    an[hh * 2 + s] = *(const u32x4*)(Att + (size_t)(m0 + row) * 512 + kof);
                    wn[hh * 2 + s] = *(const u32x4*)(Wb + (size_t)(n0 + row) * 512 + kof);
                }
        }

        #pragma unroll
        for (int s = 0; s < 2; ++s) {
            bf16x8 af0 = *(const bf16x8*)(&Ash[cur][s][(w * 16 + r16) * 64 + fr0]);
            bf16x8 af1 = *(const bf16x8*)(&Ash[cur][s][(w * 16 + r16) * 64 + fr1]);
            #pragma unroll
            for (int nc = 0; nc < 4; ++nc) {
                bf16x8 wf0 = *(const bf16x8*)(&Wsh[cur][s][(nc * 16 + r16) * 64 + fr0]);
                bf16x8 wf1 = *(const bf16x8*)(&Wsh[cur][s][(nc * 16 + r16) * 64 + fr1]);
                acc[nc] = __builtin_amdgcn_mfma_f32_16x16x32_bf16(af0, wf0, acc[nc], 0, 0, 0);
                acc[nc] = __builtin_amdgcn_mfma_f32_16x16x32_bf16(af1, wf1, acc[nc], 0, 0, 0);
            }
        }

        if (hasn) {
            const int nxt = cur ^ 1;
            #pragma unroll
            for (int hh = 0; hh < 2; ++hh)
                #pragma unroll
                for (int s = 0; s < 2; ++s) {
                    int row = hh * 32 + rr;
                    *(u32x4*)(&Ash[nxt][s][row * 64 + sw0]) = an[hh * 2 + s];
                    *(u32x4*)(&Wsh[nxt][s][row * 64 + sw0]) = wn[hh * 2 + s];
                }
        }
        __syncthreads();
    }

    #pragma unroll
    for (int nc = 0; nc < 4; ++nc) {
        float bb = bfc[n0 + nc * 16 + r16];
        #pragma unroll
        for (int r = 0; r < 4; ++r) {
            int row = m0 + w * 16 + q4 * 4 + r;
            out[(size_t)row * 512 + n0 + nc * 16 + r16] = acc[nc][r] + bb;
        }
    }
}

extern "C" void kernel_launch(void* const* d_in, const int* in_sizes, int n_in,
                              void* d_out, int out_size, void* d_ws, size_t ws_size,
                              hipStream_t stream) {
    (void)in_sizes; (void)n_in; (void)out_size; (void)ws_size;
    const float* q   = (const float*)d_in[0];
    const float* k   = (const float*)d_in[1];
    const float* v   = (const float*)d_in[2];
    const float* Wq  = (const float*)d_in[3];
    const float* Wk  = (const float*)d_in[4];
    const float* Wv  = (const float*)d_in[5];
    const float* Wfc = (const float*)d_in[6];
    const float* bfc = (const float*)d_in[7];
    float* out = (float*)d_out;

    u16* Qf = (u16*)d_ws;
    u16* Kf = Qf + 2097152;
    u16* Vf = Kf + 2097152;
    u16* At = Vf + 2097152;
    u16* Wb = At + 2097152;
    float* KnSq = (float*)((char*)d_ws + 17301504);

    proj_kernel<<<dim3(256, 1, 4), 256, 0, stream>>>(q, k, v, Wq, Wk, Wv, Wfc,
                                                     Qf, Kf, Vf, Wb, KnSq);
    flash_kernel<<<dim3(512), 512, 0, stream>>>(Qf, Kf, Vf, KnSq, At);
    fc_kernel<<<dim3(64, 8), 256, 0, stream>>>(At, Wb, bfc, out);
}